// Round 3
// baseline (465.388 us; speedup 1.0000x reference)
//
#include <hip/hip_runtime.h>

typedef __attribute__((ext_vector_type(8))) short short8;
typedef __attribute__((ext_vector_type(4))) float f32x4;

#define C_DIM 2048
#define KW 256
#define HW_DIM 4096

__device__ __forceinline__ short f2bf(float f) {
    unsigned u = __builtin_bit_cast(unsigned, f);
    unsigned r = (u + 0x7fffu + ((u >> 16) & 1u)) >> 16;
    return (short)r;
}

// ---------- Kernel 1: normalize centroid -> bf16 w_norm; zero x_hist/counts/partial ----------
__global__ __launch_bounds__(256) void k1_prep(const float* __restrict__ centroid,
                                               short* __restrict__ wnorm,
                                               float* __restrict__ xhist,
                                               int* __restrict__ counts,
                                               float4* __restrict__ partialz) {
    const int row = blockIdx.x, t = threadIdx.x;
    const float* src = centroid + row * C_DIM;
    float v[8]; float ss = 0.f;
#pragma unroll
    for (int i = 0; i < 8; ++i) { v[i] = src[t + 256 * i]; ss += v[i] * v[i]; }
#pragma unroll
    for (int off = 1; off < 64; off <<= 1) ss += __shfl_xor(ss, off);
    __shared__ float red[4];
    if ((t & 63) == 0) red[t >> 6] = ss;
    __syncthreads();
    const float tot = red[0] + red[1] + red[2] + red[3];
    const float inv = 1.0f / fmaxf(sqrtf(tot), 1e-12f);
#pragma unroll
    for (int i = 0; i < 8; ++i) wnorm[row * C_DIM + t + 256 * i] = f2bf(v[i] * inv);
    if (row == 0) {
        for (int i = t; i < 2048; i += 256) { xhist[i] = 0.f; counts[i] = 0; }
    }
    // zero the 16 MiB partial buffer (1M float4 / 65536 threads = 16 each)
    const int gid = blockIdx.x * 256 + t;
    const float4 z = {0.f, 0.f, 0.f, 0.f};
#pragma unroll
    for (int i = 0; i < 16; ++i) partialz[gid + 65536 * i] = z;
}

// ---------- Kernel 2: fused GEMM (bf16 MFMA) + norm + softmax + argmax + hist ----------
// Block: 256 thr (4 waves). Tile: M=256 k-words x N=64 pixels, K-chunk=64 channels.
// Wave w owns k-words [64w, 64w+64). grid = 32768/64 = 512 blocks.
__global__ __launch_bounds__(256, 2) void k2_main(const float* __restrict__ x,
                                                  const short* __restrict__ wnorm,
                                                  float* __restrict__ xcorr,
                                                  float* __restrict__ xhist,
                                                  int* __restrict__ labels,
                                                  int* __restrict__ counts) {
    __shared__ float sf[64 * 68];        // f32 staging tile [c:64][n stride 68]
    __shared__ short bfr[8 * 64 * 8];    // bf16 frag tile [unit:8][n:64][8c]
    __shared__ float ssred[4][64];
    __shared__ float invn[64];
    __shared__ float wmax[4][64];
    __shared__ int   warg[4][64];
    __shared__ float wred[4][64];
    __shared__ float Mn[64];
    __shared__ float Sn[64];

    const int t = threadIdx.x;
    const int w = t >> 6, l = t & 63;
    const int p = l & 15, g = l >> 4;
    const int n0 = blockIdx.x * 64;
    const int b = n0 >> 12, hw0 = n0 & 4095;
    const float* xb = x + (size_t)b * C_DIM * HW_DIM + hw0;
    const short* wrow = wnorm + (w * 64 + p) * C_DIM;

    f32x4 acc[4][4];
#pragma unroll
    for (int i = 0; i < 4; ++i)
#pragma unroll
        for (int j = 0; j < 4; ++j) acc[i][j] = (f32x4)0.f;

    float ss = 0.f;

#pragma unroll 1
    for (int cc = 0; cc < 32; ++cc) {
        const int cb = cc * 64;
#pragma unroll
        for (int q = 0; q < 4; ++q) {
            const int lin = t + q * 256;
            const int row = lin >> 4, c4 = (lin & 15) << 2;
            *(float4*)(&sf[row * 68 + c4]) =
                *(const float4*)(xb + (size_t)(cb + row) * HW_DIM + c4);
        }
        __syncthreads();
        float tv[16];
#pragma unroll
        for (int j = 0; j < 16; ++j) {
            tv[j] = sf[(16 * w + j) * 68 + l];
            ss += tv[j] * tv[j];
        }
        short8 pk0, pk1;
#pragma unroll
        for (int j = 0; j < 8; ++j) { pk0[j] = f2bf(tv[j]); pk1[j] = f2bf(tv[8 + j]); }
        *(short8*)(&bfr[((2 * w + 0) * 64 + l) * 8]) = pk0;
        *(short8*)(&bfr[((2 * w + 1) * 64 + l) * 8]) = pk1;
        __syncthreads();
#pragma unroll
        for (int ks = 0; ks < 2; ++ks) {
            short8 af[4], bf[4];
#pragma unroll
            for (int mf = 0; mf < 4; ++mf)
                af[mf] = *(const short8*)(wrow + mf * 16 * C_DIM + cb + ks * 32 + g * 8);
#pragma unroll
            for (int nf = 0; nf < 4; ++nf)
                bf[nf] = *(const short8*)(&bfr[((ks * 4 + g) * 64 + nf * 16 + p) * 8]);
#pragma unroll
            for (int mf = 0; mf < 4; ++mf)
#pragma unroll
                for (int nf = 0; nf < 4; ++nf)
                    acc[mf][nf] = __builtin_amdgcn_mfma_f32_16x16x32_bf16(
                        af[mf], bf[nf], acc[mf][nf], 0, 0, 0);
        }
        __syncthreads();
    }

    // ---- epilogue: pixel norms ----
    ssred[w][l] = ss;
    __syncthreads();
    if (t < 64) {
        const float s = ssred[0][t] + ssred[1][t] + ssred[2][t] + ssred[3][t];
        invn[t] = 1.0f / fmaxf(sqrtf(s), 1e-12f);
    }
    __syncthreads();
    float inv[4];
#pragma unroll
    for (int nf = 0; nf < 4; ++nf) inv[nf] = invn[nf * 16 + p];

    // ---- max / argmax ----
    float mx[4]; int ai[4];
#pragma unroll
    for (int nf = 0; nf < 4; ++nf) { mx[nf] = -3.0e38f; ai[nf] = 0; }
#pragma unroll
    for (int mf = 0; mf < 4; ++mf)
#pragma unroll
        for (int r = 0; r < 4; ++r) {
            const int k = w * 64 + mf * 16 + g * 4 + r;
#pragma unroll
            for (int nf = 0; nf < 4; ++nf) {
                const float v = acc[mf][nf][r] * inv[nf];
                if (v > mx[nf]) { mx[nf] = v; ai[nf] = k; }
            }
        }
#pragma unroll
    for (int off = 16; off <= 32; off <<= 1)
#pragma unroll
        for (int nf = 0; nf < 4; ++nf) {
            const float ov = __shfl_xor(mx[nf], off);
            const int   oi = __shfl_xor(ai[nf], off);
            if (ov > mx[nf] || (ov == mx[nf] && oi < ai[nf])) { mx[nf] = ov; ai[nf] = oi; }
        }
    if (l < 16) {
#pragma unroll
        for (int nf = 0; nf < 4; ++nf) { wmax[w][nf * 16 + l] = mx[nf]; warg[w][nf * 16 + l] = ai[nf]; }
    }
    __syncthreads();
    if (t < 64) {
        float m = wmax[0][t]; int a = warg[0][t];
#pragma unroll
        for (int ww = 1; ww < 4; ++ww) {
            const float om = wmax[ww][t]; const int oa = warg[ww][t];
            if (om > m || (om == m && oa < a)) { m = om; a = oa; }
        }
        Mn[t] = m;
        labels[n0 + t] = a;
        atomicAdd(&counts[b * KW + a], 1);
    }
    __syncthreads();
    float mn[4];
#pragma unroll
    for (int nf = 0; nf < 4; ++nf) mn[nf] = Mn[nf * 16 + p];

    // ---- sum of exp ----
    float se[4] = {0.f, 0.f, 0.f, 0.f};
#pragma unroll
    for (int mf = 0; mf < 4; ++mf)
#pragma unroll
        for (int r = 0; r < 4; ++r)
#pragma unroll
            for (int nf = 0; nf < 4; ++nf)
                se[nf] += __expf(acc[mf][nf][r] * inv[nf] - mn[nf]);
#pragma unroll
    for (int off = 16; off <= 32; off <<= 1)
#pragma unroll
        for (int nf = 0; nf < 4; ++nf) se[nf] += __shfl_xor(se[nf], off);
    if (l < 16) {
#pragma unroll
        for (int nf = 0; nf < 4; ++nf) wred[w][nf * 16 + l] = se[nf];
    }
    __syncthreads();
    if (t < 64) Sn[t] = wred[0][t] + wred[1][t] + wred[2][t] + wred[3][t];
    __syncthreads();

    float rs[4];
#pragma unroll
    for (int nf = 0; nf < 4; ++nf) rs[nf] = 1.0f / Sn[nf * 16 + p];

    // ---- write softmax + x_hist partials ----
    float hist[4][4];
#pragma unroll
    for (int mf = 0; mf < 4; ++mf)
#pragma unroll
        for (int r = 0; r < 4; ++r) hist[mf][r] = 0.f;
#pragma unroll
    for (int mf = 0; mf < 4; ++mf)
#pragma unroll
        for (int r = 0; r < 4; ++r) {
            const int k = w * 64 + mf * 16 + g * 4 + r;
            float* orow = xcorr + ((size_t)(b * KW + k) << 12) + hw0;
#pragma unroll
            for (int nf = 0; nf < 4; ++nf) {
                const float pr = __expf(acc[mf][nf][r] * inv[nf] - mn[nf]) * rs[nf];
                orow[nf * 16 + p] = pr;
                hist[mf][r] += pr;
            }
        }
#pragma unroll
    for (int off = 1; off <= 8; off <<= 1)
#pragma unroll
        for (int mf = 0; mf < 4; ++mf)
#pragma unroll
            for (int r = 0; r < 4; ++r) hist[mf][r] += __shfl_xor(hist[mf][r], off);
    if (p == 0) {
#pragma unroll
        for (int mf = 0; mf < 4; ++mf)
#pragma unroll
            for (int r = 0; r < 4; ++r)
                unsafeAtomicAdd(&xhist[b * KW + w * 64 + mf * 16 + g * 4 + r], hist[mf][r]);
    }
}

// ---------- Kernel 3: label scatter -> per-(batch, c-slice, pixel-group) LDS histogram ----------
// grid 2048 = 8 b x 64 c-chunks(32) x 4 pixel-groups(1024 px). LDS [256k][32c] XOR-swizzled.
// LDS accumulation via plain atomicAdd -> native ds_add_f32 (noret).
// Flush via global f32 atomics into the 8-slice partial (4 pg blocks collide per address).
__global__ __launch_bounds__(256, 4) void k3_scatter(const float* __restrict__ x,
                                                     const int* __restrict__ labels,
                                                     float* __restrict__ partial) {
    __shared__ float part[KW * 32];   // 32 KiB
    const int t = threadIdx.x;
    const int bid = blockIdx.x;
    const int ci = bid & 63;
    const int pg = (bid >> 6) & 3;
    const int b  = bid >> 8;
    for (int i = t; i < KW * 32; i += 256) part[i] = 0.f;
    __syncthreads();
    const int cb = ci * 32;
    const int pl = pg * 1024 + t * 4;
    const int4 lv = *(const int4*)(labels + b * HW_DIM + pl);
    const int a0 = lv.x << 5, a1 = lv.y << 5, a2 = lv.z << 5, a3 = lv.w << 5;
    const int s0 = lv.x & 31, s1 = lv.y & 31, s2 = lv.z & 31, s3 = lv.w & 31;
    const float* xp = x + (size_t)(b * C_DIM + cb) * HW_DIM + pl;
#pragma unroll 1
    for (int c0 = 0; c0 < 32; c0 += 8) {
        float4 v[8];
#pragma unroll
        for (int j = 0; j < 8; ++j)
            v[j] = *(const float4*)(xp + (size_t)(c0 + j) * HW_DIM);
#pragma unroll
        for (int j = 0; j < 8; ++j) {
            const int c = c0 + j;
            atomicAdd(&part[a0 + (c ^ s0)], v[j].x);
            atomicAdd(&part[a1 + (c ^ s1)], v[j].y);
            atomicAdd(&part[a2 + (c ^ s2)], v[j].z);
            atomicAdd(&part[a3 + (c ^ s3)], v[j].w);
        }
    }
    __syncthreads();
    for (int i = t; i < KW * 32; i += 256) {
        const int k = i >> 5, c = i & 31;
        unsafeAtomicAdd(&partial[((size_t)(b * KW + k) << 11) + cb + c],
                        part[(k << 5) + (c ^ (k & 31))]);
    }
}

// ---------- Kernel 4: reduce partials, EMA update, y_word ----------
__global__ __launch_bounds__(256) void k4_final(const float* __restrict__ partial,
                                                const int* __restrict__ counts,
                                                const float* __restrict__ centroid,
                                                float* __restrict__ out_c,
                                                float* __restrict__ y_word) {
    const int idx = blockIdx.x * 256 + threadIdx.x;   // 0..524287
    const int k = idx >> 11, c = idx & 2047;
    float s = 0.f;
#pragma unroll
    for (int pi = 0; pi < 8; ++pi) s += partial[((size_t)(pi * KW + k) << 11) + c];
    int cnt = 0;
#pragma unroll
    for (int bb = 0; bb < 8; ++bb) cnt += counts[bb * KW + k];
    const float ctr = s / ((float)cnt + 1e-4f);
    out_c[idx] = 0.01f * ctr + 0.99f * centroid[idx];
    if (idx < 2048) y_word[idx] = (counts[idx] > 0) ? 1.0f : 0.0f;
}

extern "C" void kernel_launch(void* const* d_in, const int* in_sizes, int n_in,
                              void* d_out, int out_size, void* d_ws, size_t ws_size,
                              hipStream_t stream) {
    const float* x        = (const float*)d_in[0];
    const float* centroid = (const float*)d_in[1];
    float* out   = (float*)d_out;
    float* xcorr = out;                 // 8*256*4096
    float* xhist = out + 8388608;       // 2048
    float* yword = out + 8390656;       // 2048
    float* outc  = out + 8392704;       // 256*2048

    char* ws = (char*)d_ws;
    short* wnorm   = (short*)ws;                                    // 1 MiB
    int*   labels  = (int*)(ws + (1 << 20));                        // 128 KiB
    int*   counts  = (int*)(ws + (1 << 20) + 131072);               // 8 KiB
    float* partial = (float*)(ws + (1 << 20) + 131072 + 8192);      // 16 MiB

    hipLaunchKernelGGL(k1_prep,    dim3(256),  dim3(256), 0, stream, centroid, wnorm, xhist, counts, (float4*)partial);
    hipLaunchKernelGGL(k2_main,    dim3(512),  dim3(256), 0, stream, x, wnorm, xcorr, xhist, labels, counts);
    hipLaunchKernelGGL(k3_scatter, dim3(2048), dim3(256), 0, stream, x, labels, partial);
    hipLaunchKernelGGL(k4_final,   dim3(2048), dim3(256), 0, stream, partial, counts, centroid, outc, yword);
}

// Round 4
// 282.276 us; speedup vs baseline: 1.6487x; 1.6487x over previous
//
#include <hip/hip_runtime.h>

typedef __attribute__((ext_vector_type(8))) short short8;
typedef __attribute__((ext_vector_type(4))) float f32x4;

#define C_DIM 2048
#define KW 256
#define HW_DIM 4096

__device__ __forceinline__ short f2bf(float f) {
    unsigned u = __builtin_bit_cast(unsigned, f);
    unsigned r = (u + 0x7fffu + ((u >> 16) & 1u)) >> 16;
    return (short)r;
}

// ---------- Kernel 1: normalize centroid -> bf16 w_norm; zero x_hist/counts ----------
__global__ __launch_bounds__(256) void k1_prep(const float* __restrict__ centroid,
                                               short* __restrict__ wnorm,
                                               float* __restrict__ xhist,
                                               int* __restrict__ counts) {
    const int row = blockIdx.x, t = threadIdx.x;
    const float* src = centroid + row * C_DIM;
    float v[8]; float ss = 0.f;
#pragma unroll
    for (int i = 0; i < 8; ++i) { v[i] = src[t + 256 * i]; ss += v[i] * v[i]; }
#pragma unroll
    for (int off = 1; off < 64; off <<= 1) ss += __shfl_xor(ss, off);
    __shared__ float red[4];
    if ((t & 63) == 0) red[t >> 6] = ss;
    __syncthreads();
    const float tot = red[0] + red[1] + red[2] + red[3];
    const float inv = 1.0f / fmaxf(sqrtf(tot), 1e-12f);
#pragma unroll
    for (int i = 0; i < 8; ++i) wnorm[row * C_DIM + t + 256 * i] = f2bf(v[i] * inv);
    if (row == 0) {
        for (int i = t; i < 2048; i += 256) { xhist[i] = 0.f; counts[i] = 0; }
    }
}

// ---------- Kernel 2: fused GEMM (bf16 MFMA) + norm + softmax + argmax + hist ----------
// Block: 256 thr (4 waves). Tile: M=256 k-words x N=64 pixels, K-chunk=64 channels.
__global__ __launch_bounds__(256, 2) void k2_main(const float* __restrict__ x,
                                                  const short* __restrict__ wnorm,
                                                  float* __restrict__ xcorr,
                                                  float* __restrict__ xhist,
                                                  int* __restrict__ labels,
                                                  int* __restrict__ counts) {
    __shared__ float sf[64 * 68];        // f32 staging tile [c:64][n stride 68]
    __shared__ short bfr[8 * 64 * 8];    // bf16 frag tile [unit:8][n:64][8c]
    __shared__ float ssred[4][64];
    __shared__ float invn[64];
    __shared__ float wmax[4][64];
    __shared__ int   warg[4][64];
    __shared__ float wred[4][64];
    __shared__ float Mn[64];
    __shared__ float Sn[64];

    const int t = threadIdx.x;
    const int w = t >> 6, l = t & 63;
    const int p = l & 15, g = l >> 4;
    const int n0 = blockIdx.x * 64;
    const int b = n0 >> 12, hw0 = n0 & 4095;
    const float* xb = x + (size_t)b * C_DIM * HW_DIM + hw0;
    const short* wrow = wnorm + (w * 64 + p) * C_DIM;

    f32x4 acc[4][4];
#pragma unroll
    for (int i = 0; i < 4; ++i)
#pragma unroll
        for (int j = 0; j < 4; ++j) acc[i][j] = (f32x4)0.f;

    float ss = 0.f;

#pragma unroll 1
    for (int cc = 0; cc < 32; ++cc) {
        const int cb = cc * 64;
#pragma unroll
        for (int q = 0; q < 4; ++q) {
            const int lin = t + q * 256;
            const int row = lin >> 4, c4 = (lin & 15) << 2;
            *(float4*)(&sf[row * 68 + c4]) =
                *(const float4*)(xb + (size_t)(cb + row) * HW_DIM + c4);
        }
        __syncthreads();
        float tv[16];
#pragma unroll
        for (int j = 0; j < 16; ++j) {
            tv[j] = sf[(16 * w + j) * 68 + l];
            ss += tv[j] * tv[j];
        }
        short8 pk0, pk1;
#pragma unroll
        for (int j = 0; j < 8; ++j) { pk0[j] = f2bf(tv[j]); pk1[j] = f2bf(tv[8 + j]); }
        *(short8*)(&bfr[((2 * w + 0) * 64 + l) * 8]) = pk0;
        *(short8*)(&bfr[((2 * w + 1) * 64 + l) * 8]) = pk1;
        __syncthreads();
#pragma unroll
        for (int ks = 0; ks < 2; ++ks) {
            short8 af[4], bf[4];
#pragma unroll
            for (int mf = 0; mf < 4; ++mf)
                af[mf] = *(const short8*)(wrow + mf * 16 * C_DIM + cb + ks * 32 + g * 8);
#pragma unroll
            for (int nf = 0; nf < 4; ++nf)
                bf[nf] = *(const short8*)(&bfr[((ks * 4 + g) * 64 + nf * 16 + p) * 8]);
#pragma unroll
            for (int mf = 0; mf < 4; ++mf)
#pragma unroll
                for (int nf = 0; nf < 4; ++nf)
                    acc[mf][nf] = __builtin_amdgcn_mfma_f32_16x16x32_bf16(
                        af[mf], bf[nf], acc[mf][nf], 0, 0, 0);
        }
        __syncthreads();
    }

    // ---- epilogue: pixel norms ----
    ssred[w][l] = ss;
    __syncthreads();
    if (t < 64) {
        const float s = ssred[0][t] + ssred[1][t] + ssred[2][t] + ssred[3][t];
        invn[t] = 1.0f / fmaxf(sqrtf(s), 1e-12f);
    }
    __syncthreads();
    float inv[4];
#pragma unroll
    for (int nf = 0; nf < 4; ++nf) inv[nf] = invn[nf * 16 + p];

    // ---- max / argmax ----
    float mx[4]; int ai[4];
#pragma unroll
    for (int nf = 0; nf < 4; ++nf) { mx[nf] = -3.0e38f; ai[nf] = 0; }
#pragma unroll
    for (int mf = 0; mf < 4; ++mf)
#pragma unroll
        for (int r = 0; r < 4; ++r) {
            const int k = w * 64 + mf * 16 + g * 4 + r;
#pragma unroll
            for (int nf = 0; nf < 4; ++nf) {
                const float v = acc[mf][nf][r] * inv[nf];
                if (v > mx[nf]) { mx[nf] = v; ai[nf] = k; }
            }
        }
#pragma unroll
    for (int off = 16; off <= 32; off <<= 1)
#pragma unroll
        for (int nf = 0; nf < 4; ++nf) {
            const float ov = __shfl_xor(mx[nf], off);
            const int   oi = __shfl_xor(ai[nf], off);
            if (ov > mx[nf] || (ov == mx[nf] && oi < ai[nf])) { mx[nf] = ov; ai[nf] = oi; }
        }
    if (l < 16) {
#pragma unroll
        for (int nf = 0; nf < 4; ++nf) { wmax[w][nf * 16 + l] = mx[nf]; warg[w][nf * 16 + l] = ai[nf]; }
    }
    __syncthreads();
    if (t < 64) {
        float m = wmax[0][t]; int a = warg[0][t];
#pragma unroll
        for (int ww = 1; ww < 4; ++ww) {
            const float om = wmax[ww][t]; const int oa = warg[ww][t];
            if (om > m || (om == m && oa < a)) { m = om; a = oa; }
        }
        Mn[t] = m;
        labels[n0 + t] = a;
        atomicAdd(&counts[b * KW + a], 1);
    }
    __syncthreads();
    float mn[4];
#pragma unroll
    for (int nf = 0; nf < 4; ++nf) mn[nf] = Mn[nf * 16 + p];

    // ---- sum of exp ----
    float se[4] = {0.f, 0.f, 0.f, 0.f};
#pragma unroll
    for (int mf = 0; mf < 4; ++mf)
#pragma unroll
        for (int r = 0; r < 4; ++r)
#pragma unroll
            for (int nf = 0; nf < 4; ++nf)
                se[nf] += __expf(acc[mf][nf][r] * inv[nf] - mn[nf]);
#pragma unroll
    for (int off = 16; off <= 32; off <<= 1)
#pragma unroll
        for (int nf = 0; nf < 4; ++nf) se[nf] += __shfl_xor(se[nf], off);
    if (l < 16) {
#pragma unroll
        for (int nf = 0; nf < 4; ++nf) wred[w][nf * 16 + l] = se[nf];
    }
    __syncthreads();
    if (t < 64) Sn[t] = wred[0][t] + wred[1][t] + wred[2][t] + wred[3][t];
    __syncthreads();

    float rs[4];
#pragma unroll
    for (int nf = 0; nf < 4; ++nf) rs[nf] = 1.0f / Sn[nf * 16 + p];

    // ---- write softmax + x_hist partials ----
    float hist[4][4];
#pragma unroll
    for (int mf = 0; mf < 4; ++mf)
#pragma unroll
        for (int r = 0; r < 4; ++r) hist[mf][r] = 0.f;
#pragma unroll
    for (int mf = 0; mf < 4; ++mf)
#pragma unroll
        for (int r = 0; r < 4; ++r) {
            const int k = w * 64 + mf * 16 + g * 4 + r;
            float* orow = xcorr + ((size_t)(b * KW + k) << 12) + hw0;
#pragma unroll
            for (int nf = 0; nf < 4; ++nf) {
                const float pr = __expf(acc[mf][nf][r] * inv[nf] - mn[nf]) * rs[nf];
                orow[nf * 16 + p] = pr;
                hist[mf][r] += pr;
            }
        }
#pragma unroll
    for (int off = 1; off <= 8; off <<= 1)
#pragma unroll
        for (int mf = 0; mf < 4; ++mf)
#pragma unroll
            for (int r = 0; r < 4; ++r) hist[mf][r] += __shfl_xor(hist[mf][r], off);
    if (p == 0) {
#pragma unroll
        for (int mf = 0; mf < 4; ++mf)
#pragma unroll
            for (int r = 0; r < 4; ++r)
                unsafeAtomicAdd(&xhist[b * KW + w * 64 + mf * 16 + g * 4 + r], hist[mf][r]);
    }
}

// ---------- Kernel 3: MFMA segmented-sum  ctr_partial[b][k][c] = sum_px onehot[k,px] * x[c,px] ----------
// grid 256 = 8 b x 32 c-chunks(64c). 4 waves/block, each wave owns 16 c.
// A = onehot [16k x 32px] built in regs from LDS labels; B = x [32px x 16c] loaded
// f32 global -> bf16 regs (8 contiguous px per lane). No atomics; exclusive output.
__global__ __launch_bounds__(256, 1) void k3_ctr(const float* __restrict__ x,
                                                 const int* __restrict__ labels,
                                                 float* __restrict__ partial) {
    __shared__ int lab[HW_DIM];   // 16 KiB
    const int t = threadIdx.x;
    const int w = t >> 6, l = t & 63;
    const int p = l & 15, g = l >> 4;
    const int b = blockIdx.x >> 5, cc = blockIdx.x & 31;
    {
        const int4* src = (const int4*)(labels + b * HW_DIM);
        int4* dst = (int4*)lab;
        for (int i = t; i < HW_DIM / 4; i += 256) dst[i] = src[i];
    }
    __syncthreads();

    const int c0 = cc * 64 + w * 16 + p;
    const float* xrow = x + ((size_t)b * C_DIM + c0) * HW_DIM;

    f32x4 acc[16];
#pragma unroll
    for (int mf = 0; mf < 16; ++mf) acc[mf] = (f32x4)0.f;

    // prefetch iter 0
    float4 b0 = *(const float4*)(xrow + g * 8);
    float4 b1 = *(const float4*)(xrow + g * 8 + 4);

#pragma unroll 1
    for (int px0 = 0; px0 < HW_DIM; px0 += 32) {
        // labels for this wave's 8 k-elements (broadcast reads)
        const int4 L0 = *(const int4*)(&lab[px0 + g * 8]);
        const int4 L1 = *(const int4*)(&lab[px0 + g * 8 + 4]);
        // prefetch next iteration's B (clamped re-load on last iter)
        const int pxn = (px0 + 32 < HW_DIM) ? (px0 + 32) : px0;
        float4 n0 = *(const float4*)(xrow + pxn + g * 8);
        float4 n1 = *(const float4*)(xrow + pxn + g * 8 + 4);

        short8 bf;
        bf[0] = f2bf(b0.x); bf[1] = f2bf(b0.y); bf[2] = f2bf(b0.z); bf[3] = f2bf(b0.w);
        bf[4] = f2bf(b1.x); bf[5] = f2bf(b1.y); bf[6] = f2bf(b1.z); bf[7] = f2bf(b1.w);

        const int lj0 = L0.x, lj1 = L0.y, lj2 = L0.z, lj3 = L0.w;
        const int lj4 = L1.x, lj5 = L1.y, lj6 = L1.z, lj7 = L1.w;
#pragma unroll
        for (int mf = 0; mf < 16; ++mf) {
            const int tgt = mf * 16 + p;
            short8 af;
            af[0] = (lj0 == tgt) ? (short)0x3F80 : (short)0;
            af[1] = (lj1 == tgt) ? (short)0x3F80 : (short)0;
            af[2] = (lj2 == tgt) ? (short)0x3F80 : (short)0;
            af[3] = (lj3 == tgt) ? (short)0x3F80 : (short)0;
            af[4] = (lj4 == tgt) ? (short)0x3F80 : (short)0;
            af[5] = (lj5 == tgt) ? (short)0x3F80 : (short)0;
            af[6] = (lj6 == tgt) ? (short)0x3F80 : (short)0;
            af[7] = (lj7 == tgt) ? (short)0x3F80 : (short)0;
            acc[mf] = __builtin_amdgcn_mfma_f32_16x16x32_bf16(af, bf, acc[mf], 0, 0, 0);
        }
        b0 = n0; b1 = n1;
    }

    // write ctr partial: D row = k-word (mf*16 + g*4 + r), col = c0. Exclusive.
#pragma unroll
    for (int mf = 0; mf < 16; ++mf)
#pragma unroll
        for (int r = 0; r < 4; ++r)
            partial[((size_t)(b * KW + mf * 16 + g * 4 + r) << 11) + c0] = acc[mf][r];
}

// ---------- Kernel 4: reduce partials, EMA update, y_word ----------
__global__ __launch_bounds__(256) void k4_final(const float* __restrict__ partial,
                                                const int* __restrict__ counts,
                                                const float* __restrict__ centroid,
                                                float* __restrict__ out_c,
                                                float* __restrict__ y_word) {
    const int idx = blockIdx.x * 256 + threadIdx.x;   // 0..524287
    const int k = idx >> 11, c = idx & 2047;
    float s = 0.f;
#pragma unroll
    for (int pi = 0; pi < 8; ++pi) s += partial[((size_t)(pi * KW + k) << 11) + c];
    int cnt = 0;
#pragma unroll
    for (int bb = 0; bb < 8; ++bb) cnt += counts[bb * KW + k];
    const float ctr = s / ((float)cnt + 1e-4f);
    out_c[idx] = 0.01f * ctr + 0.99f * centroid[idx];
    if (idx < 2048) y_word[idx] = (counts[idx] > 0) ? 1.0f : 0.0f;
}

extern "C" void kernel_launch(void* const* d_in, const int* in_sizes, int n_in,
                              void* d_out, int out_size, void* d_ws, size_t ws_size,
                              hipStream_t stream) {
    const float* x        = (const float*)d_in[0];
    const float* centroid = (const float*)d_in[1];
    float* out   = (float*)d_out;
    float* xcorr = out;                 // 8*256*4096
    float* xhist = out + 8388608;       // 2048
    float* yword = out + 8390656;       // 2048
    float* outc  = out + 8392704;       // 256*2048

    char* ws = (char*)d_ws;
    short* wnorm   = (short*)ws;                                    // 1 MiB
    int*   labels  = (int*)(ws + (1 << 20));                        // 128 KiB
    int*   counts  = (int*)(ws + (1 << 20) + 131072);               // 8 KiB
    float* partial = (float*)(ws + (1 << 20) + 131072 + 8192);      // 16 MiB

    hipLaunchKernelGGL(k1_prep,  dim3(256),  dim3(256), 0, stream, centroid, wnorm, xhist, counts);
    hipLaunchKernelGGL(k2_main,  dim3(512),  dim3(256), 0, stream, x, wnorm, xcorr, xhist, labels, counts);
    hipLaunchKernelGGL(k3_ctr,   dim3(256),  dim3(256), 0, stream, x, labels, partial);
    hipLaunchKernelGGL(k4_final, dim3(2048), dim3(256), 0, stream, partial, counts, centroid, outc, yword);
}

// Round 5
// 211.627 us; speedup vs baseline: 2.1991x; 1.3338x over previous
//
#include <hip/hip_runtime.h>

typedef __attribute__((ext_vector_type(8))) short short8;
typedef __attribute__((ext_vector_type(4))) float f32x4;
typedef __attribute__((ext_vector_type(4))) unsigned int u32x4;

#define C_DIM 2048
#define KW 256
#define HW_DIM 4096

__device__ __forceinline__ short f2bf(float f) {
    unsigned u = __builtin_bit_cast(unsigned, f);
    unsigned r = (u + 0x7fffu + ((u >> 16) & 1u)) >> 16;
    return (short)r;
}

// ---------- Kernel 1: normalize centroid -> bf16 w_norm; zero x_hist/counts/partial ----------
__global__ __launch_bounds__(256) void k1_prep(const float* __restrict__ centroid,
                                               short* __restrict__ wnorm,
                                               float* __restrict__ xhist,
                                               int* __restrict__ counts,
                                               float4* __restrict__ partialz) {
    const int row = blockIdx.x, t = threadIdx.x;
    const float* src = centroid + row * C_DIM;
    float v[8]; float ss = 0.f;
#pragma unroll
    for (int i = 0; i < 8; ++i) { v[i] = src[t + 256 * i]; ss += v[i] * v[i]; }
#pragma unroll
    for (int off = 1; off < 64; off <<= 1) ss += __shfl_xor(ss, off);
    __shared__ float red[4];
    if ((t & 63) == 0) red[t >> 6] = ss;
    __syncthreads();
    const float tot = red[0] + red[1] + red[2] + red[3];
    const float inv = 1.0f / fmaxf(sqrtf(tot), 1e-12f);
#pragma unroll
    for (int i = 0; i < 8; ++i) wnorm[row * C_DIM + t + 256 * i] = f2bf(v[i] * inv);
    if (row == 0) {
        for (int i = t; i < 2048; i += 256) { xhist[i] = 0.f; counts[i] = 0; }
    }
    // zero the 16 MiB partial buffer (1M float4 / 65536 threads = 16 each)
    const int gid = blockIdx.x * 256 + t;
    const float4 z = {0.f, 0.f, 0.f, 0.f};
#pragma unroll
    for (int i = 0; i < 16; ++i) partialz[gid + 65536 * i] = z;
}

// ---------- Kernel 2: fused GEMM (bf16 MFMA) + norm + softmax + argmax + hist ----------
// Block: 256 thr (4 waves). Tile: M=256 k-words x N=64 pixels, K-chunk=64 channels.
__global__ __launch_bounds__(256, 2) void k2_main(const float* __restrict__ x,
                                                  const short* __restrict__ wnorm,
                                                  float* __restrict__ xcorr,
                                                  float* __restrict__ xhist,
                                                  int* __restrict__ labels,
                                                  int* __restrict__ counts) {
    __shared__ float sf[64 * 68];        // f32 staging tile [c:64][n stride 68]
    __shared__ short bfr[8 * 64 * 8];    // bf16 frag tile [unit:8][n:64][8c]
    __shared__ float ssred[4][64];
    __shared__ float invn[64];
    __shared__ float wmax[4][64];
    __shared__ int   warg[4][64];
    __shared__ float wred[4][64];
    __shared__ float Mn[64];
    __shared__ float Sn[64];

    const int t = threadIdx.x;
    const int w = t >> 6, l = t & 63;
    const int p = l & 15, g = l >> 4;
    const int n0 = blockIdx.x * 64;
    const int b = n0 >> 12, hw0 = n0 & 4095;
    const float* xb = x + (size_t)b * C_DIM * HW_DIM + hw0;
    const short* wrow = wnorm + (w * 64 + p) * C_DIM;

    f32x4 acc[4][4];
#pragma unroll
    for (int i = 0; i < 4; ++i)
#pragma unroll
        for (int j = 0; j < 4; ++j) acc[i][j] = (f32x4)0.f;

    float ss = 0.f;

#pragma unroll 1
    for (int cc = 0; cc < 32; ++cc) {
        const int cb = cc * 64;
#pragma unroll
        for (int q = 0; q < 4; ++q) {
            const int lin = t + q * 256;
            const int row = lin >> 4, c4 = (lin & 15) << 2;
            *(float4*)(&sf[row * 68 + c4]) =
                *(const float4*)(xb + (size_t)(cb + row) * HW_DIM + c4);
        }
        __syncthreads();
        float tv[16];
#pragma unroll
        for (int j = 0; j < 16; ++j) {
            tv[j] = sf[(16 * w + j) * 68 + l];
            ss += tv[j] * tv[j];
        }
        short8 pk0, pk1;
#pragma unroll
        for (int j = 0; j < 8; ++j) { pk0[j] = f2bf(tv[j]); pk1[j] = f2bf(tv[8 + j]); }
        *(short8*)(&bfr[((2 * w + 0) * 64 + l) * 8]) = pk0;
        *(short8*)(&bfr[((2 * w + 1) * 64 + l) * 8]) = pk1;
        __syncthreads();
#pragma unroll
        for (int ks = 0; ks < 2; ++ks) {
            short8 af[4], bf[4];
#pragma unroll
            for (int mf = 0; mf < 4; ++mf)
                af[mf] = *(const short8*)(wrow + mf * 16 * C_DIM + cb + ks * 32 + g * 8);
#pragma unroll
            for (int nf = 0; nf < 4; ++nf)
                bf[nf] = *(const short8*)(&bfr[((ks * 4 + g) * 64 + nf * 16 + p) * 8]);
#pragma unroll
            for (int mf = 0; mf < 4; ++mf)
#pragma unroll
                for (int nf = 0; nf < 4; ++nf)
                    acc[mf][nf] = __builtin_amdgcn_mfma_f32_16x16x32_bf16(
                        af[mf], bf[nf], acc[mf][nf], 0, 0, 0);
        }
        __syncthreads();
    }

    // ---- epilogue: pixel norms ----
    ssred[w][l] = ss;
    __syncthreads();
    if (t < 64) {
        const float s = ssred[0][t] + ssred[1][t] + ssred[2][t] + ssred[3][t];
        invn[t] = 1.0f / fmaxf(sqrtf(s), 1e-12f);
    }
    __syncthreads();
    float inv[4];
#pragma unroll
    for (int nf = 0; nf < 4; ++nf) inv[nf] = invn[nf * 16 + p];

    // ---- max / argmax ----
    float mx[4]; int ai[4];
#pragma unroll
    for (int nf = 0; nf < 4; ++nf) { mx[nf] = -3.0e38f; ai[nf] = 0; }
#pragma unroll
    for (int mf = 0; mf < 4; ++mf)
#pragma unroll
        for (int r = 0; r < 4; ++r) {
            const int k = w * 64 + mf * 16 + g * 4 + r;
#pragma unroll
            for (int nf = 0; nf < 4; ++nf) {
                const float v = acc[mf][nf][r] * inv[nf];
                if (v > mx[nf]) { mx[nf] = v; ai[nf] = k; }
            }
        }
#pragma unroll
    for (int off = 16; off <= 32; off <<= 1)
#pragma unroll
        for (int nf = 0; nf < 4; ++nf) {
            const float ov = __shfl_xor(mx[nf], off);
            const int   oi = __shfl_xor(ai[nf], off);
            if (ov > mx[nf] || (ov == mx[nf] && oi < ai[nf])) { mx[nf] = ov; ai[nf] = oi; }
        }
    if (l < 16) {
#pragma unroll
        for (int nf = 0; nf < 4; ++nf) { wmax[w][nf * 16 + l] = mx[nf]; warg[w][nf * 16 + l] = ai[nf]; }
    }
    __syncthreads();
    if (t < 64) {
        float m = wmax[0][t]; int a = warg[0][t];
#pragma unroll
        for (int ww = 1; ww < 4; ++ww) {
            const float om = wmax[ww][t]; const int oa = warg[ww][t];
            if (om > m || (om == m && oa < a)) { m = om; a = oa; }
        }
        Mn[t] = m;
        labels[n0 + t] = a;
        atomicAdd(&counts[b * KW + a], 1);
    }
    __syncthreads();
    float mn[4];
#pragma unroll
    for (int nf = 0; nf < 4; ++nf) mn[nf] = Mn[nf * 16 + p];

    // ---- sum of exp ----
    float se[4] = {0.f, 0.f, 0.f, 0.f};
#pragma unroll
    for (int mf = 0; mf < 4; ++mf)
#pragma unroll
        for (int r = 0; r < 4; ++r)
#pragma unroll
            for (int nf = 0; nf < 4; ++nf)
                se[nf] += __expf(acc[mf][nf][r] * inv[nf] - mn[nf]);
#pragma unroll
    for (int off = 16; off <= 32; off <<= 1)
#pragma unroll
        for (int nf = 0; nf < 4; ++nf) se[nf] += __shfl_xor(se[nf], off);
    if (l < 16) {
#pragma unroll
        for (int nf = 0; nf < 4; ++nf) wred[w][nf * 16 + l] = se[nf];
    }
    __syncthreads();
    if (t < 64) Sn[t] = wred[0][t] + wred[1][t] + wred[2][t] + wred[3][t];
    __syncthreads();

    float rs[4];
#pragma unroll
    for (int nf = 0; nf < 4; ++nf) rs[nf] = 1.0f / Sn[nf * 16 + p];

    // ---- write softmax + x_hist partials ----
    float hist[4][4];
#pragma unroll
    for (int mf = 0; mf < 4; ++mf)
#pragma unroll
        for (int r = 0; r < 4; ++r) hist[mf][r] = 0.f;
#pragma unroll
    for (int mf = 0; mf < 4; ++mf)
#pragma unroll
        for (int r = 0; r < 4; ++r) {
            const int k = w * 64 + mf * 16 + g * 4 + r;
            float* orow = xcorr + ((size_t)(b * KW + k) << 12) + hw0;
#pragma unroll
            for (int nf = 0; nf < 4; ++nf) {
                const float pr = __expf(acc[mf][nf][r] * inv[nf] - mn[nf]) * rs[nf];
                orow[nf * 16 + p] = pr;
                hist[mf][r] += pr;
            }
        }
#pragma unroll
    for (int off = 1; off <= 8; off <<= 1)
#pragma unroll
        for (int mf = 0; mf < 4; ++mf)
#pragma unroll
            for (int r = 0; r < 4; ++r) hist[mf][r] += __shfl_xor(hist[mf][r], off);
    if (p == 0) {
#pragma unroll
        for (int mf = 0; mf < 4; ++mf)
#pragma unroll
            for (int r = 0; r < 4; ++r)
                unsafeAtomicAdd(&xhist[b * KW + w * 64 + mf * 16 + g * 4 + r], hist[mf][r]);
    }
}

// ---------- Kernel 3: MFMA segmented-sum  ctr_partial[b][k][c] += sum_px onehot[k,px] * x[c,px] ----------
// grid 1024 = 8 b x 4 px-groups(1024px) x 32 c-chunks(64c). 4 waves/block, each wave owns 16 c.
// A = onehot built via bit-mask trick; B = x f32->bf16 regs. Flush: global f32 atomics (4 pg collide).
__global__ __launch_bounds__(256, 4) void k3_ctr(const float* __restrict__ x,
                                                 const int* __restrict__ labels,
                                                 float* __restrict__ partial) {
    __shared__ int lab[1024];   // 4 KiB
    const int t = threadIdx.x;
    const int w = t >> 6, l = t & 63;
    const int p = l & 15, g = l >> 4;
    const int cc = blockIdx.x & 31;
    const int pg = (blockIdx.x >> 5) & 3;
    const int b  = blockIdx.x >> 7;
    if (t < 256) ((int4*)lab)[t] = ((const int4*)(labels + b * HW_DIM + pg * 1024))[t];
    __syncthreads();

    const int c0 = cc * 64 + w * 16 + p;
    const float* xrow = x + ((size_t)b * C_DIM + c0) * HW_DIM + pg * 1024;

    f32x4 acc[16];
#pragma unroll
    for (int mf = 0; mf < 16; ++mf) acc[mf] = (f32x4)0.f;

    // prefetch iter 0
    float4 b0 = *(const float4*)(xrow + g * 8);
    float4 b1 = *(const float4*)(xrow + g * 8 + 4);

#pragma unroll 1
    for (int px0 = 0; px0 < 1024; px0 += 32) {
        const int4 L0 = *(const int4*)(&lab[px0 + g * 8]);
        const int4 L1 = *(const int4*)(&lab[px0 + g * 8 + 4]);
        const int pxn = (px0 + 32 < 1024) ? (px0 + 32) : px0;
        float4 n0 = *(const float4*)(xrow + pxn + g * 8);
        float4 n1 = *(const float4*)(xrow + pxn + g * 8 + 4);

        short8 bf;
        bf[0] = f2bf(b0.x); bf[1] = f2bf(b0.y); bf[2] = f2bf(b0.z); bf[3] = f2bf(b0.w);
        bf[4] = f2bf(b1.x); bf[5] = f2bf(b1.y); bf[6] = f2bf(b1.z); bf[7] = f2bf(b1.w);

        // bit-mask one-hot: bits_j has bit (lj>>4) set iff (lj&15)==p
        const int lj[8] = {L0.x, L0.y, L0.z, L0.w, L1.x, L1.y, L1.z, L1.w};
        unsigned bits[8];
#pragma unroll
        for (int j = 0; j < 8; ++j)
            bits[j] = ((lj[j] & 15) == p) ? (1u << (lj[j] >> 4)) : 0u;
        unsigned cmb[4];
#pragma unroll
        for (int a = 0; a < 4; ++a) cmb[a] = bits[2 * a] | (bits[2 * a + 1] << 16);

#pragma unroll
        for (int mf = 0; mf < 16; ++mf) {
            u32x4 ar;
#pragma unroll
            for (int a = 0; a < 4; ++a)
                ar[a] = ((cmb[a] >> mf) & 0x00010001u) * 0x3F80u;
            acc[mf] = __builtin_amdgcn_mfma_f32_16x16x32_bf16(
                __builtin_bit_cast(short8, ar), bf, acc[mf], 0, 0, 0);
        }
        b0 = n0; b1 = n1;
    }

    // flush: atomic add into the b-slice (4 pg blocks collide per address)
#pragma unroll
    for (int mf = 0; mf < 16; ++mf)
#pragma unroll
        for (int r = 0; r < 4; ++r)
            unsafeAtomicAdd(&partial[((size_t)(b * KW + mf * 16 + g * 4 + r) << 11) + c0],
                            acc[mf][r]);
}

// ---------- Kernel 4: reduce partials, EMA update, y_word ----------
__global__ __launch_bounds__(256) void k4_final(const float* __restrict__ partial,
                                                const int* __restrict__ counts,
                                                const float* __restrict__ centroid,
                                                float* __restrict__ out_c,
                                                float* __restrict__ y_word) {
    const int idx = blockIdx.x * 256 + threadIdx.x;   // 0..524287
    const int k = idx >> 11, c = idx & 2047;
    float s = 0.f;
#pragma unroll
    for (int pi = 0; pi < 8; ++pi) s += partial[((size_t)(pi * KW + k) << 11) + c];
    int cnt = 0;
#pragma unroll
    for (int bb = 0; bb < 8; ++bb) cnt += counts[bb * KW + k];
    const float ctr = s / ((float)cnt + 1e-4f);
    out_c[idx] = 0.01f * ctr + 0.99f * centroid[idx];
    if (idx < 2048) y_word[idx] = (counts[idx] > 0) ? 1.0f : 0.0f;
}

extern "C" void kernel_launch(void* const* d_in, const int* in_sizes, int n_in,
                              void* d_out, int out_size, void* d_ws, size_t ws_size,
                              hipStream_t stream) {
    const float* x        = (const float*)d_in[0];
    const float* centroid = (const float*)d_in[1];
    float* out   = (float*)d_out;
    float* xcorr = out;                 // 8*256*4096
    float* xhist = out + 8388608;       // 2048
    float* yword = out + 8390656;       // 2048
    float* outc  = out + 8392704;       // 256*2048

    char* ws = (char*)d_ws;
    short* wnorm   = (short*)ws;                                    // 1 MiB
    int*   labels  = (int*)(ws + (1 << 20));                        // 128 KiB
    int*   counts  = (int*)(ws + (1 << 20) + 131072);               // 8 KiB
    float* partial = (float*)(ws + (1 << 20) + 131072 + 8192);      // 16 MiB

    hipLaunchKernelGGL(k1_prep,  dim3(256),  dim3(256), 0, stream, centroid, wnorm, xhist, counts, (float4*)partial);
    hipLaunchKernelGGL(k2_main,  dim3(512),  dim3(256), 0, stream, x, wnorm, xcorr, xhist, labels, counts);
    hipLaunchKernelGGL(k3_ctr,   dim3(1024), dim3(256), 0, stream, x, labels, partial);
    hipLaunchKernelGGL(k4_final, dim3(2048), dim3(256), 0, stream, partial, counts, centroid, outc, yword);
}

// Round 6
// 194.071 us; speedup vs baseline: 2.3980x; 1.0905x over previous
//
#include <hip/hip_runtime.h>

typedef __attribute__((ext_vector_type(8))) short short8;
typedef __attribute__((ext_vector_type(4))) float f32x4;
typedef __attribute__((ext_vector_type(4))) unsigned int u32x4;

#define C_DIM 2048
#define KW 256
#define HW_DIM 4096

__device__ __forceinline__ short f2bf(float f) {
    unsigned u = __builtin_bit_cast(unsigned, f);
    unsigned r = (u + 0x7fffu + ((u >> 16) & 1u)) >> 16;
    return (short)r;
}

// ---------- Kernel 1: normalize centroid -> bf16 w_norm in k2's FRAGMENT layout ----------
// wt layout: [cc(32)][ks(2)][g(4)][k(256)][c8(8)], c = cc*64 + ks*32 + g*8 + c8.
// Also zeroes x_hist/counts/partial.
__global__ __launch_bounds__(256) void k1_prep(const float* __restrict__ centroid,
                                               short* __restrict__ wt,
                                               float* __restrict__ xhist,
                                               int* __restrict__ counts,
                                               float4* __restrict__ partialz) {
    const int row = blockIdx.x, t = threadIdx.x;
    const float* src = centroid + row * C_DIM;
    float v[8]; float ss = 0.f;
#pragma unroll
    for (int i = 0; i < 8; ++i) { v[i] = src[t + 256 * i]; ss += v[i] * v[i]; }
#pragma unroll
    for (int off = 1; off < 64; off <<= 1) ss += __shfl_xor(ss, off);
    __shared__ float red[4];
    if ((t & 63) == 0) red[t >> 6] = ss;
    __syncthreads();
    const float tot = red[0] + red[1] + red[2] + red[3];
    const float inv = 1.0f / fmaxf(sqrtf(tot), 1e-12f);
#pragma unroll
    for (int i = 0; i < 8; ++i) {
        const int c = t + 256 * i;
        const int idx = ((((c >> 6) * 2 + ((c >> 5) & 1)) * 4 + ((c >> 3) & 3)) * 256 + row) * 8 + (c & 7);
        wt[idx] = f2bf(v[i] * inv);
    }
    if (row == 0) {
        for (int i = t; i < 2048; i += 256) { xhist[i] = 0.f; counts[i] = 0; }
    }
    // zero the 16 MiB partial buffer (1M float4 / 65536 threads = 16 each)
    const int gid = blockIdx.x * 256 + t;
    const float4 z = {0.f, 0.f, 0.f, 0.f};
#pragma unroll
    for (int i = 0; i < 16; ++i) partialz[gid + 65536 * i] = z;
}

// ---------- Kernel 2: fused GEMM (bf16 MFMA) + norm + softmax + argmax + hist ----------
// Block: 256 thr (4 waves). Tile: M=256 k-words x N=64 pixels, K-chunk=64 channels.
// A-fragments come from wt (pre-swizzled) -> coalesced wave loads.
__global__ __launch_bounds__(256, 3) void k2_main(const float* __restrict__ x,
                                                  const short* __restrict__ wt,
                                                  float* __restrict__ xcorr,
                                                  float* __restrict__ xhist,
                                                  int* __restrict__ labels,
                                                  int* __restrict__ counts) {
    __shared__ float sf[64 * 68];        // f32 staging tile [c:64][n stride 68]
    __shared__ short bfr[8 * 64 * 8];    // bf16 frag tile [unit:8][n:64][8c]
    __shared__ float ssred[4][64];
    __shared__ float invn[64];
    __shared__ float wmax[4][64];
    __shared__ int   warg[4][64];
    __shared__ float wred[4][64];
    __shared__ float Mn[64];
    __shared__ float Sn[64];

    const int t = threadIdx.x;
    const int w = t >> 6, l = t & 63;
    const int p = l & 15, g = l >> 4;
    const int n0 = blockIdx.x * 64;
    const int b = n0 >> 12, hw0 = n0 & 4095;
    const float* xb = x + (size_t)b * C_DIM * HW_DIM + hw0;

    f32x4 acc[4][4];
#pragma unroll
    for (int i = 0; i < 4; ++i)
#pragma unroll
        for (int j = 0; j < 4; ++j) acc[i][j] = (f32x4)0.f;

    float ss = 0.f;

#pragma unroll 1
    for (int cc = 0; cc < 32; ++cc) {
        const int cb = cc * 64;
#pragma unroll
        for (int q = 0; q < 4; ++q) {
            const int lin = t + q * 256;
            const int row = lin >> 4, c4 = (lin & 15) << 2;
            *(float4*)(&sf[row * 68 + c4]) =
                *(const float4*)(xb + (size_t)(cb + row) * HW_DIM + c4);
        }
        __syncthreads();
        float tv[16];
#pragma unroll
        for (int j = 0; j < 16; ++j) {
            tv[j] = sf[(16 * w + j) * 68 + l];
            ss += tv[j] * tv[j];
        }
        short8 pk0, pk1;
#pragma unroll
        for (int j = 0; j < 8; ++j) { pk0[j] = f2bf(tv[j]); pk1[j] = f2bf(tv[8 + j]); }
        *(short8*)(&bfr[((2 * w + 0) * 64 + l) * 8]) = pk0;
        *(short8*)(&bfr[((2 * w + 1) * 64 + l) * 8]) = pk1;
        __syncthreads();
#pragma unroll
        for (int ks = 0; ks < 2; ++ks) {
            short8 af[4], bf[4];
#pragma unroll
            for (int mf = 0; mf < 4; ++mf)
                af[mf] = *(const short8*)(wt + (((size_t)(cc * 2 + ks) * 4 + g) * 256 + (w * 64 + mf * 16 + p)) * 8);
#pragma unroll
            for (int nf = 0; nf < 4; ++nf)
                bf[nf] = *(const short8*)(&bfr[((ks * 4 + g) * 64 + nf * 16 + p) * 8]);
#pragma unroll
            for (int mf = 0; mf < 4; ++mf)
#pragma unroll
                for (int nf = 0; nf < 4; ++nf)
                    acc[mf][nf] = __builtin_amdgcn_mfma_f32_16x16x32_bf16(
                        af[mf], bf[nf], acc[mf][nf], 0, 0, 0);
        }
        __syncthreads();
    }

    // ---- epilogue: pixel norms ----
    ssred[w][l] = ss;
    __syncthreads();
    if (t < 64) {
        const float s = ssred[0][t] + ssred[1][t] + ssred[2][t] + ssred[3][t];
        invn[t] = 1.0f / fmaxf(sqrtf(s), 1e-12f);
    }
    __syncthreads();
    float inv[4];
#pragma unroll
    for (int nf = 0; nf < 4; ++nf) inv[nf] = invn[nf * 16 + p];

    // ---- max / argmax ----
    float mx[4]; int ai[4];
#pragma unroll
    for (int nf = 0; nf < 4; ++nf) { mx[nf] = -3.0e38f; ai[nf] = 0; }
#pragma unroll
    for (int mf = 0; mf < 4; ++mf)
#pragma unroll
        for (int r = 0; r < 4; ++r) {
            const int k = w * 64 + mf * 16 + g * 4 + r;
#pragma unroll
            for (int nf = 0; nf < 4; ++nf) {
                const float v = acc[mf][nf][r] * inv[nf];
                if (v > mx[nf]) { mx[nf] = v; ai[nf] = k; }
            }
        }
#pragma unroll
    for (int off = 16; off <= 32; off <<= 1)
#pragma unroll
        for (int nf = 0; nf < 4; ++nf) {
            const float ov = __shfl_xor(mx[nf], off);
            const int   oi = __shfl_xor(ai[nf], off);
            if (ov > mx[nf] || (ov == mx[nf] && oi < ai[nf])) { mx[nf] = ov; ai[nf] = oi; }
        }
    if (l < 16) {
#pragma unroll
        for (int nf = 0; nf < 4; ++nf) { wmax[w][nf * 16 + l] = mx[nf]; warg[w][nf * 16 + l] = ai[nf]; }
    }
    __syncthreads();
    if (t < 64) {
        float m = wmax[0][t]; int a = warg[0][t];
#pragma unroll
        for (int ww = 1; ww < 4; ++ww) {
            const float om = wmax[ww][t]; const int oa = warg[ww][t];
            if (om > m || (om == m && oa < a)) { m = om; a = oa; }
        }
        Mn[t] = m;
        labels[n0 + t] = a;
        atomicAdd(&counts[b * KW + a], 1);
    }
    __syncthreads();
    float mn[4];
#pragma unroll
    for (int nf = 0; nf < 4; ++nf) mn[nf] = Mn[nf * 16 + p];

    // ---- sum of exp ----
    float se[4] = {0.f, 0.f, 0.f, 0.f};
#pragma unroll
    for (int mf = 0; mf < 4; ++mf)
#pragma unroll
        for (int r = 0; r < 4; ++r)
#pragma unroll
            for (int nf = 0; nf < 4; ++nf)
                se[nf] += __expf(acc[mf][nf][r] * inv[nf] - mn[nf]);
#pragma unroll
    for (int off = 16; off <= 32; off <<= 1)
#pragma unroll
        for (int nf = 0; nf < 4; ++nf) se[nf] += __shfl_xor(se[nf], off);
    if (l < 16) {
#pragma unroll
        for (int nf = 0; nf < 4; ++nf) wred[w][nf * 16 + l] = se[nf];
    }
    __syncthreads();
    if (t < 64) Sn[t] = wred[0][t] + wred[1][t] + wred[2][t] + wred[3][t];
    __syncthreads();

    float rs[4];
#pragma unroll
    for (int nf = 0; nf < 4; ++nf) rs[nf] = 1.0f / Sn[nf * 16 + p];

    // ---- write softmax + x_hist partials ----
    float hist[4][4];
#pragma unroll
    for (int mf = 0; mf < 4; ++mf)
#pragma unroll
        for (int r = 0; r < 4; ++r) hist[mf][r] = 0.f;
#pragma unroll
    for (int mf = 0; mf < 4; ++mf)
#pragma unroll
        for (int r = 0; r < 4; ++r) {
            const int k = w * 64 + mf * 16 + g * 4 + r;
            float* orow = xcorr + ((size_t)(b * KW + k) << 12) + hw0;
#pragma unroll
            for (int nf = 0; nf < 4; ++nf) {
                const float pr = __expf(acc[mf][nf][r] * inv[nf] - mn[nf]) * rs[nf];
                orow[nf * 16 + p] = pr;
                hist[mf][r] += pr;
            }
        }
#pragma unroll
    for (int off = 1; off <= 8; off <<= 1)
#pragma unroll
        for (int mf = 0; mf < 4; ++mf)
#pragma unroll
            for (int r = 0; r < 4; ++r) hist[mf][r] += __shfl_xor(hist[mf][r], off);
    if (p == 0) {
#pragma unroll
        for (int mf = 0; mf < 4; ++mf)
#pragma unroll
            for (int r = 0; r < 4; ++r)
                unsafeAtomicAdd(&xhist[b * KW + w * 64 + mf * 16 + g * 4 + r], hist[mf][r]);
    }
}

// ---------- Kernel 3: MFMA segmented-sum, 2 c-chunks per wave (A-build amortized) ----------
// grid 512 = 8 b x 4 px-groups(1024px) x 16 c-chunks(128c). Wave owns 32 c (two 16-c frags).
__global__ __launch_bounds__(256, 2) void k3_ctr(const float* __restrict__ x,
                                                 const int* __restrict__ labels,
                                                 float* __restrict__ partial) {
    __shared__ int lab[1024];   // 4 KiB
    const int t = threadIdx.x;
    const int w = t >> 6, l = t & 63;
    const int p = l & 15, g = l >> 4;
    const int cc = blockIdx.x & 15;
    const int pg = (blockIdx.x >> 4) & 3;
    const int b  = blockIdx.x >> 6;
    ((int4*)lab)[t] = ((const int4*)(labels + b * HW_DIM + pg * 1024))[t];
    __syncthreads();

    const int c0 = cc * 128 + w * 32 + p;
    const int c1 = c0 + 16;
    const float* xr0 = x + ((size_t)b * C_DIM + c0) * HW_DIM + pg * 1024;
    const float* xr1 = x + ((size_t)b * C_DIM + c1) * HW_DIM + pg * 1024;

    f32x4 accA[16], accB[16];
#pragma unroll
    for (int mf = 0; mf < 16; ++mf) { accA[mf] = (f32x4)0.f; accB[mf] = (f32x4)0.f; }

    // prefetch iter 0
    float4 a0 = *(const float4*)(xr0 + g * 8);
    float4 a1 = *(const float4*)(xr0 + g * 8 + 4);
    float4 e0 = *(const float4*)(xr1 + g * 8);
    float4 e1 = *(const float4*)(xr1 + g * 8 + 4);

#pragma unroll 1
    for (int px0 = 0; px0 < 1024; px0 += 32) {
        const int4 L0 = *(const int4*)(&lab[px0 + g * 8]);
        const int4 L1 = *(const int4*)(&lab[px0 + g * 8 + 4]);
        const int pxn = (px0 + 32 < 1024) ? (px0 + 32) : px0;
        float4 na0 = *(const float4*)(xr0 + pxn + g * 8);
        float4 na1 = *(const float4*)(xr0 + pxn + g * 8 + 4);
        float4 ne0 = *(const float4*)(xr1 + pxn + g * 8);
        float4 ne1 = *(const float4*)(xr1 + pxn + g * 8 + 4);

        short8 bfA, bfB;
        bfA[0] = f2bf(a0.x); bfA[1] = f2bf(a0.y); bfA[2] = f2bf(a0.z); bfA[3] = f2bf(a0.w);
        bfA[4] = f2bf(a1.x); bfA[5] = f2bf(a1.y); bfA[6] = f2bf(a1.z); bfA[7] = f2bf(a1.w);
        bfB[0] = f2bf(e0.x); bfB[1] = f2bf(e0.y); bfB[2] = f2bf(e0.z); bfB[3] = f2bf(e0.w);
        bfB[4] = f2bf(e1.x); bfB[5] = f2bf(e1.y); bfB[6] = f2bf(e1.z); bfB[7] = f2bf(e1.w);

        // bit-mask one-hot: bits_j has bit (lj>>4) set iff (lj&15)==p
        const int lj[8] = {L0.x, L0.y, L0.z, L0.w, L1.x, L1.y, L1.z, L1.w};
        unsigned bits[8];
#pragma unroll
        for (int j = 0; j < 8; ++j)
            bits[j] = ((lj[j] & 15) == p) ? (1u << (lj[j] >> 4)) : 0u;
        const unsigned cmb0 = bits[0] | (bits[1] << 16);
        const unsigned cmb1 = bits[2] | (bits[3] << 16);
        const unsigned cmb2 = bits[4] | (bits[5] << 16);
        const unsigned cmb3 = bits[6] | (bits[7] << 16);

#pragma unroll
        for (int mf = 0; mf < 16; ++mf) {
            u32x4 ar;
            ar[0] = ((cmb0 >> mf) & 0x00010001u) * 0x3F80u;
            ar[1] = ((cmb1 >> mf) & 0x00010001u) * 0x3F80u;
            ar[2] = ((cmb2 >> mf) & 0x00010001u) * 0x3F80u;
            ar[3] = ((cmb3 >> mf) & 0x00010001u) * 0x3F80u;
            const short8 af = __builtin_bit_cast(short8, ar);
            accA[mf] = __builtin_amdgcn_mfma_f32_16x16x32_bf16(af, bfA, accA[mf], 0, 0, 0);
            accB[mf] = __builtin_amdgcn_mfma_f32_16x16x32_bf16(af, bfB, accB[mf], 0, 0, 0);
        }
        a0 = na0; a1 = na1; e0 = ne0; e1 = ne1;
    }

    // flush: atomic add into the b-slice (4 pg blocks collide per address)
#pragma unroll
    for (int mf = 0; mf < 16; ++mf)
#pragma unroll
        for (int r = 0; r < 4; ++r) {
            const size_t rowoff = (size_t)(b * KW + mf * 16 + g * 4 + r) << 11;
            unsafeAtomicAdd(&partial[rowoff + c0], accA[mf][r]);
            unsafeAtomicAdd(&partial[rowoff + c1], accB[mf][r]);
        }
}

// ---------- Kernel 4: reduce partials, EMA update, y_word ----------
__global__ __launch_bounds__(256) void k4_final(const float* __restrict__ partial,
                                                const int* __restrict__ counts,
                                                const float* __restrict__ centroid,
                                                float* __restrict__ out_c,
                                                float* __restrict__ y_word) {
    const int idx = blockIdx.x * 256 + threadIdx.x;   // 0..524287
    const int k = idx >> 11, c = idx & 2047;
    float s = 0.f;
#pragma unroll
    for (int pi = 0; pi < 8; ++pi) s += partial[((size_t)(pi * KW + k) << 11) + c];
    int cnt = 0;
#pragma unroll
    for (int bb = 0; bb < 8; ++bb) cnt += counts[bb * KW + k];
    const float ctr = s / ((float)cnt + 1e-4f);
    out_c[idx] = 0.01f * ctr + 0.99f * centroid[idx];
    if (idx < 2048) y_word[idx] = (counts[idx] > 0) ? 1.0f : 0.0f;
}

extern "C" void kernel_launch(void* const* d_in, const int* in_sizes, int n_in,
                              void* d_out, int out_size, void* d_ws, size_t ws_size,
                              hipStream_t stream) {
    const float* x        = (const float*)d_in[0];
    const float* centroid = (const float*)d_in[1];
    float* out   = (float*)d_out;
    float* xcorr = out;                 // 8*256*4096
    float* xhist = out + 8388608;       // 2048
    float* yword = out + 8390656;       // 2048
    float* outc  = out + 8392704;       // 256*2048

    char* ws = (char*)d_ws;
    short* wt      = (short*)ws;                                    // 1 MiB (fragment layout)
    int*   labels  = (int*)(ws + (1 << 20));                        // 128 KiB
    int*   counts  = (int*)(ws + (1 << 20) + 131072);               // 8 KiB
    float* partial = (float*)(ws + (1 << 20) + 131072 + 8192);      // 16 MiB

    hipLaunchKernelGGL(k1_prep,  dim3(256),  dim3(256), 0, stream, centroid, wt, xhist, counts, (float4*)partial);
    hipLaunchKernelGGL(k2_main,  dim3(512),  dim3(256), 0, stream, x, wt, xcorr, xhist, labels, counts);
    hipLaunchKernelGGL(k3_ctr,   dim3(512),  dim3(256), 0, stream, x, labels, partial);
    hipLaunchKernelGGL(k4_final, dim3(2048), dim3(256), 0, stream, partial, counts, centroid, outc, yword);
}